// Round 4
// baseline (219.586 us; speedup 1.0000x reference)
//
#include <hip/hip_runtime.h>
#include <math.h>

#define H 512
#define W 512
#define NPIX (32LL*512*512)

// per-wave private vch slice: [6 ch][4 rows][42 cols] = 1008 floats.
// 8 waves * 1008 * 4B = 32256 B (+ssum) -> 4 blocks/CU, 32 waves/CU.
#define VCH(wid,ch,u,c) uni[(wid)*1008 + (ch)*168 + (u)*42 + (c)]

// order-preserving float->uint encoding so we can use native atomicMax(u32).
// enc(x) > 0 for all reals, so a 0-initialized slot acts as -inf.
__device__ inline unsigned encf(float f) {
    unsigned u = __float_as_uint(f);
    return (u & 0x80000000u) ? ~u : (u | 0x80000000u);
}
__device__ inline float decf(unsigned e) {
    unsigned u = (e & 0x80000000u) ? (e ^ 0x80000000u) : ~e;
    return __uint_as_float(u);
}

__global__ __launch_bounds__(256) void maxred_kernel(
        const float* __restrict__ in, const float* __restrict__ tg,
        const float* __restrict__ mk, unsigned* __restrict__ mx) {
    const float4* in4 = (const float4*)in;
    const float4* tg4 = (const float4*)tg;
    const float4* mk4 = (const float4*)mk;
    long long n4 = NPIX / 4;
    long long idx = (long long)blockIdx.x * blockDim.x + threadIdx.x;
    long long stride = (long long)gridDim.x * blockDim.x;
    float ma = -INFINITY, mb = -INFINITY;   // two independent chains
    for (long long i = idx; i < n4; i += stride) {
        float4 a = in4[i], b = tg4[i], c = mk4[i];
        ma = fmaxf(ma, fmaxf(fmaxf(a.x * c.x, a.y * c.y), fmaxf(a.z * c.z, a.w * c.w)));
        mb = fmaxf(mb, fmaxf(fmaxf(b.x * c.x, b.y * c.y), fmaxf(b.z * c.z, b.w * c.w)));
    }
    float m = fmaxf(ma, mb);
    #pragma unroll
    for (int off = 32; off; off >>= 1) m = fmaxf(m, __shfl_down(m, off, 64));
    __shared__ float smax[4];
    int lane = threadIdx.x & 63, wid = threadIdx.x >> 6;
    if (lane == 0) smax[wid] = m;
    __syncthreads();
    if (threadIdx.x == 0) {
        float r = fmaxf(fmaxf(smax[0], smax[1]), fmaxf(smax[2], smax[3]));
        atomicMax(mx, encf(r));
    }
}

__global__ __launch_bounds__(512, 8) void ssim_kernel(
        const float* __restrict__ in, const float* __restrict__ tg,
        const float* __restrict__ mk, const float* __restrict__ win,
        const unsigned* __restrict__ mxp, double* __restrict__ sum) {
    __shared__ __align__(16) float uni[8064];
    __shared__ float ssum[8];

    int t = threadIdx.x;
    int lane = t & 63, wid = t >> 6;

    // ---- per-wave: separable 1-D gaussian weights -> SGPRs (no LDS, no barrier)
    float rs = 0.f;
    if (lane < 11) {
        #pragma unroll
        for (int j = 0; j < 11; j++) rs += win[lane * 11 + j];
    }
    float wk[11];
    #pragma unroll
    for (int k = 0; k < 11; k++)
        wk[k] = __uint_as_float(__builtin_amdgcn_readfirstlane(
                    __float_as_uint(__shfl(rs, k, 64))));

    // uniform scalar from the max pass (used only in the epilogue)
    float L = decf(*mxp);
    float C3 = 0.5f * (0.03f * L) * (0.03f * L);

    int img = blockIdx.z;
    int y0w = blockIdx.y * 32 + wid * 4;   // this wave's 4 output rows
    int x0  = blockIdx.x * 32;
    const size_t base = (size_t)img * H * W;
    const float* __restrict__ inb = in + base;
    const float* __restrict__ tgb = tg + base;
    const float* __restrict__ mkb = mk + base;

    // ---- vertical blur: lanes 0..41 each own one staged column, 4 output rows.
    // acc[6][4] = 24 VGPRs: fits the 8-wave/SIMD 64-reg budget with pipelining slack.
    if (lane < 42) {
        int x = x0 - 5 + lane;
        bool inx = (unsigned)x < (unsigned)W;
        int xc = inx ? x : 0;                  // clamped: loads always legal
        float xs = inx ? 1.f : 0.f;
        int ybase = y0w - 5;

        float acc[6][4];
        #pragma unroll
        for (int ch = 0; ch < 6; ch++)
            #pragma unroll
            for (int u = 0; u < 4; u++) acc[ch][u] = 0.f;

        if (ybase >= 0 && ybase <= H - 14) {
            // interior fast path: unconditional loads, strength-reduced address
            size_t g = (size_t)ybase * W + xc;
            #pragma unroll
            for (int j = 0; j < 14; j++) {
                float iv = inb[g], tv = tgb[g], m = mkb[g] * xs;
                g += W;
                float a = iv * m, b = tv * m;
                float v[6] = { m, a, b, a * a, b * b, a * b };
                #pragma unroll
                for (int u = 0; u < 4; u++) {
                    int k = j - u;
                    if (k >= 0 && k < 11) {            // compile-time pruned
                        float w = wk[k];
                        #pragma unroll
                        for (int ch = 0; ch < 6; ch++)
                            acc[ch][u] = fmaf(w, v[ch], acc[ch][u]);
                    }
                }
            }
        } else {
            // y-edge strips (top/bottom of the image only)
            #pragma unroll
            for (int j = 0; j < 14; j++) {
                int y = ybase + j;
                bool yok = (unsigned)y < (unsigned)H;
                size_t g = (size_t)(yok ? y : 0) * W + xc;
                float sc = yok ? xs : 0.f;
                float iv = inb[g], tv = tgb[g], m = mkb[g] * sc;
                float a = iv * m, b = tv * m;
                float v[6] = { m, a, b, a * a, b * b, a * b };
                #pragma unroll
                for (int u = 0; u < 4; u++) {
                    int k = j - u;
                    if (k >= 0 && k < 11) {
                        float w = wk[k];
                        #pragma unroll
                        for (int ch = 0; ch < 6; ch++)
                            acc[ch][u] = fmaf(w, v[ch], acc[ch][u]);
                    }
                }
            }
        }
        #pragma unroll
        for (int u = 0; u < 4; u++)
            #pragma unroll
            for (int ch = 0; ch < 6; ch++) VCH(wid, ch, u, lane) = acc[ch][u];
    }

    // ---- wave-local LDS RAW fence: producer wave == consumer wave, so a
    // counted wait replaces __syncthreads (sched_barrier after asm wait: rule #18)
    __builtin_amdgcn_wave_barrier();
    asm volatile("s_waitcnt lgkmcnt(0)" ::: "memory");
    __builtin_amdgcn_sched_barrier(0);

    // ---- horizontal blur + structure map: lane -> (row = lane>>4, 2 cols)
    int r = lane >> 4, c0 = (lane & 15) << 1;
    float hs[6][2];
    #pragma unroll
    for (int ch = 0; ch < 6; ch++) {
        float Wl[12];
        #pragma unroll
        for (int q = 0; q < 6; q++) {
            float2 v = *(const float2*)&VCH(wid, ch, r, c0 + 2 * q);
            Wl[2 * q] = v.x; Wl[2 * q + 1] = v.y;
        }
        #pragma unroll
        for (int u = 0; u < 2; u++) {
            float h = 0.f;
            #pragma unroll
            for (int k = 0; k < 11; k++) h = fmaf(wk[k], Wl[u + k], h);
            hs[ch][u] = h;
        }
    }

    // structure map with num/den multiplied through by mw^2 (no per-pixel divide):
    //   num = hs5*mw - hs1*hs2 + C3*mw^2
    //   den = sqrt(Xi*Xt) + (C3+1e-8)*mw^2,  Xi = max(hs3*mw - hs1^2,0) + 1e-12*mw^2
    float lsum = 0.f;
    #pragma unroll
    for (int u = 0; u < 2; u++) {
        float h1 = hs[1][u], h2 = hs[2][u];
        float mw = hs[0][u] + 1e-8f;
        float mw2 = mw * mw;
        float e12 = 1e-12f * mw2;
        float Xi = fmaxf(fmaf(hs[3][u], mw, -h1 * h1), 0.f) + e12;
        float Xt = fmaxf(fmaf(hs[4][u], mw, -h2 * h2), 0.f) + e12;
        float num = fmaf(hs[5][u], mw, -h1 * h2) + C3 * mw2;
        float den = __builtin_amdgcn_sqrtf(Xi * Xt) + (C3 + 1e-8f) * mw2;
        lsum += num * __builtin_amdgcn_rcpf(den);
    }

    #pragma unroll
    for (int off = 32; off; off >>= 1) lsum += __shfl_down(lsum, off, 64);
    if (lane == 0) ssum[wid] = lsum;
    __syncthreads();                 // only block-wide barrier (final reduce)
    if (t == 0) {
        float tot = 0.f;
        #pragma unroll
        for (int w = 0; w < 8; w++) tot += ssum[w];
        atomicAdd(sum, (double)tot);
    }
}

__global__ void fin_kernel(const double* __restrict__ sum, float* __restrict__ out) {
    out[0] = 1.0f - (float)(*sum / (double)NPIX);
}

extern "C" void kernel_launch(void* const* d_in, const int* in_sizes, int n_in,
                              void* d_out, int out_size, void* d_ws, size_t ws_size,
                              hipStream_t stream) {
    const float* in  = (const float*)d_in[0];
    const float* tg  = (const float*)d_in[1];
    const float* mk  = (const float*)d_in[2];
    const float* win = (const float*)d_in[3];
    float* out = (float*)d_out;

    double*   dsum = (double*)d_ws;
    unsigned* dmax = (unsigned*)((char*)d_ws + 8);

    // dsum = 0.0, dmax = 0 (order-encoding floor) in one stream-ordered memset
    hipMemsetAsync(d_ws, 0, 12, stream);
    maxred_kernel<<<2048, 256, 0, stream>>>(in, tg, mk, dmax);
    ssim_kernel<<<dim3(16, 16, 32), 512, 0, stream>>>(in, tg, mk, win, dmax, dsum);
    fin_kernel<<<1, 1, 0, stream>>>(dsum, out);
}

// Round 5
// 186.988 us; speedup vs baseline: 1.1743x; 1.1743x over previous
//
#include <hip/hip_runtime.h>
#include <math.h>

#define H 512
#define W 512
#define NPIX (32LL*512*512)

// per-wave private vch slice: [6 ch][8 rows][42 cols] = 2016 floats.
// 4 waves * 2016 * 4B = 32256 B (+gw+ssum) -> 32768 alloc -> 5 blocks/CU.
#define VCH(wid,ch,u,c) uni[(wid)*2016 + (ch)*336 + (u)*42 + (c)]

// order-preserving float->uint encoding so we can use native atomicMax(u32).
// enc(x) > 0 for all reals, so a 0-initialized slot acts as -inf.
__device__ inline unsigned encf(float f) {
    unsigned u = __float_as_uint(f);
    return (u & 0x80000000u) ? ~u : (u | 0x80000000u);
}
__device__ inline float decf(unsigned e) {
    unsigned u = (e & 0x80000000u) ? (e ^ 0x80000000u) : ~e;
    return __uint_as_float(u);
}

__global__ __launch_bounds__(256) void maxred_kernel(
        const float* __restrict__ in, const float* __restrict__ tg,
        const float* __restrict__ mk, unsigned* __restrict__ mx) {
    const float4* in4 = (const float4*)in;
    const float4* tg4 = (const float4*)tg;
    const float4* mk4 = (const float4*)mk;
    long long n4 = NPIX / 4;
    long long idx = (long long)blockIdx.x * blockDim.x + threadIdx.x;
    long long stride = (long long)gridDim.x * blockDim.x;
    // 8 independent per-component max chains (no serial fmax tree in the loop)
    float4 A = make_float4(-INFINITY, -INFINITY, -INFINITY, -INFINITY);
    float4 B = A;
    for (long long i = idx; i < n4; i += stride) {
        float4 a = in4[i], b = tg4[i], c = mk4[i];
        A.x = fmaxf(A.x, a.x * c.x); A.y = fmaxf(A.y, a.y * c.y);
        A.z = fmaxf(A.z, a.z * c.z); A.w = fmaxf(A.w, a.w * c.w);
        B.x = fmaxf(B.x, b.x * c.x); B.y = fmaxf(B.y, b.y * c.y);
        B.z = fmaxf(B.z, b.z * c.z); B.w = fmaxf(B.w, b.w * c.w);
    }
    float m = fmaxf(fmaxf(fmaxf(A.x, A.y), fmaxf(A.z, A.w)),
                    fmaxf(fmaxf(B.x, B.y), fmaxf(B.z, B.w)));
    #pragma unroll
    for (int off = 32; off; off >>= 1) m = fmaxf(m, __shfl_down(m, off, 64));
    __shared__ float smax[4];
    int lane = threadIdx.x & 63, wid = threadIdx.x >> 6;
    if (lane == 0) smax[wid] = m;
    __syncthreads();
    if (threadIdx.x == 0) {
        float r = fmaxf(fmaxf(smax[0], smax[1]), fmaxf(smax[2], smax[3]));
        atomicMax(mx, encf(r));
    }
}

// (256,5): guarantee the 5 blocks/CU that 32KB LDS already dictates ->
// VGPR cap 102; anything <=102 costs zero occupancy, so no reason to spill.
__global__ __launch_bounds__(256, 5) void ssim_kernel(
        const float* __restrict__ in, const float* __restrict__ tg,
        const float* __restrict__ mk, const float* __restrict__ win,
        const unsigned* __restrict__ mxp, double* __restrict__ sum) {
    __shared__ __align__(16) float uni[8064];
    __shared__ float gw[11];
    __shared__ float ssum[4];

    int t = threadIdx.x;
    int lane = t & 63, wid = t >> 6;

    if (t < 11) {
        float s = 0.f;
        #pragma unroll
        for (int j = 0; j < 11; j++) s += win[t * 11 + j];
        gw[t] = s;   // separable 1-D gaussian (row sums of outer(g,g); sum==1)
    }
    // uniform scalar from the max pass (scalar load; used only in the epilogue)
    float L = decf(*mxp);
    float C3 = 0.5f * (0.03f * L) * (0.03f * L);
    __syncthreads();

    // weights -> SGPRs via LDS broadcast + readfirstlane (R1-verified, no spill)
    float wk[11];
    #pragma unroll
    for (int k = 0; k < 11; k++)
        wk[k] = __uint_as_float(__builtin_amdgcn_readfirstlane(__float_as_uint(gw[k])));

    int img = blockIdx.z;
    int y0w = blockIdx.y * 32 + wid * 8;   // this wave's 8 output rows
    int x0  = blockIdx.x * 32;
    const size_t base = (size_t)img * H * W;
    const float* __restrict__ inb = in + base;
    const float* __restrict__ tgb = tg + base;
    const float* __restrict__ mkb = mk + base;

    // ---- vertical blur: lanes 0..41 each own one staged column, 8 output rows.
    if (lane < 42) {
        int x = x0 - 5 + lane;
        bool inx = (unsigned)x < (unsigned)W;
        int xc = inx ? x : 0;                  // clamped: loads always legal
        float xs = inx ? 1.f : 0.f;
        int ybase = y0w - 5;

        float acc[6][8];
        #pragma unroll
        for (int ch = 0; ch < 6; ch++)
            #pragma unroll
            for (int u = 0; u < 8; u++) acc[ch][u] = 0.f;

        if (ybase >= 0 && ybase <= H - 18) {
            // interior: explicit 4-row register prefetch (use-then-fill ring,
            // fully unrolled -> static slot indices, ~400 FMA cycles of cover)
            size_t g = (size_t)ybase * W + xc;
            float pi[4], pt[4], pm[4];
            #pragma unroll
            for (int p = 0; p < 4; p++) {
                pi[p] = inb[g]; pt[p] = tgb[g]; pm[p] = mkb[g];
                g += W;
            }
            #pragma unroll
            for (int j = 0; j < 18; j++) {
                float iv = pi[j & 3], tv = pt[j & 3], m = pm[j & 3] * xs;
                if (j + 4 < 18) {              // refill the slot just consumed
                    pi[j & 3] = inb[g]; pt[j & 3] = tgb[g]; pm[j & 3] = mkb[g];
                    g += W;
                }
                float a = iv * m, b = tv * m;
                float v[6] = { m, a, b, a * a, b * b, a * b };
                #pragma unroll
                for (int u = 0; u < 8; u++) {
                    int k = j - u;
                    if (k >= 0 && k < 11) {    // compile-time pruned
                        float w = wk[k];
                        #pragma unroll
                        for (int ch = 0; ch < 6; ch++)
                            acc[ch][u] = fmaf(w, v[ch], acc[ch][u]);
                    }
                }
            }
        } else {
            // y-edge strips (top/bottom of the image only)
            #pragma unroll
            for (int j = 0; j < 18; j++) {
                int y = ybase + j;
                bool yok = (unsigned)y < (unsigned)H;
                size_t g = (size_t)(yok ? y : 0) * W + xc;
                float sc = yok ? xs : 0.f;
                float iv = inb[g], tv = tgb[g], m = mkb[g] * sc;
                float a = iv * m, b = tv * m;
                float v[6] = { m, a, b, a * a, b * b, a * b };
                #pragma unroll
                for (int u = 0; u < 8; u++) {
                    int k = j - u;
                    if (k >= 0 && k < 11) {
                        float w = wk[k];
                        #pragma unroll
                        for (int ch = 0; ch < 6; ch++)
                            acc[ch][u] = fmaf(w, v[ch], acc[ch][u]);
                    }
                }
            }
        }
        #pragma unroll
        for (int u = 0; u < 8; u++)
            #pragma unroll
            for (int ch = 0; ch < 6; ch++) VCH(wid, ch, u, lane) = acc[ch][u];
    }

    // ---- wave-local LDS RAW fence: producer wave == consumer wave, so a
    // counted wait replaces __syncthreads (sched_barrier after asm wait: rule #18)
    __builtin_amdgcn_wave_barrier();
    asm volatile("s_waitcnt lgkmcnt(0)" ::: "memory");
    __builtin_amdgcn_sched_barrier(0);

    // ---- horizontal blur + structure map: lane -> (row = lane>>3, 4 cols)
    int r = lane >> 3, c0 = (lane & 7) << 2;
    float hs[6][4];
    #pragma unroll
    for (int ch = 0; ch < 6; ch++) {
        float Wl[14];
        #pragma unroll
        for (int q = 0; q < 7; q++) {
            float2 v = *(const float2*)&VCH(wid, ch, r, c0 + 2 * q);
            Wl[2 * q] = v.x; Wl[2 * q + 1] = v.y;
        }
        #pragma unroll
        for (int u = 0; u < 4; u++) {
            float h = 0.f;
            #pragma unroll
            for (int k = 0; k < 11; k++) h = fmaf(wk[k], Wl[u + k], h);
            hs[ch][u] = h;
        }
    }

    // structure map with num/den multiplied through by mw^2 (no per-pixel divide):
    //   num = hs5*mw - hs1*hs2 + C3*mw^2
    //   den = sqrt(Xi*Xt) + (C3+1e-8)*mw^2,  Xi = max(hs3*mw - hs1^2,0) + 1e-12*mw^2
    float lsum = 0.f;
    #pragma unroll
    for (int u = 0; u < 4; u++) {
        float h1 = hs[1][u], h2 = hs[2][u];
        float mw = hs[0][u] + 1e-8f;
        float mw2 = mw * mw;
        float e12 = 1e-12f * mw2;
        float Xi = fmaxf(fmaf(hs[3][u], mw, -h1 * h1), 0.f) + e12;
        float Xt = fmaxf(fmaf(hs[4][u], mw, -h2 * h2), 0.f) + e12;
        float num = fmaf(hs[5][u], mw, -h1 * h2) + C3 * mw2;
        float den = __builtin_amdgcn_sqrtf(Xi * Xt) + (C3 + 1e-8f) * mw2;
        lsum += num * __builtin_amdgcn_rcpf(den);
    }

    #pragma unroll
    for (int off = 32; off; off >>= 1) lsum += __shfl_down(lsum, off, 64);
    if (lane == 0) ssum[wid] = lsum;
    __syncthreads();                 // only block-wide barrier (final reduce)
    if (t == 0) {
        float tot = ssum[0] + ssum[1] + ssum[2] + ssum[3];
        atomicAdd(sum, (double)tot);
    }
}

__global__ void fin_kernel(const double* __restrict__ sum, float* __restrict__ out) {
    out[0] = 1.0f - (float)(*sum / (double)NPIX);
}

extern "C" void kernel_launch(void* const* d_in, const int* in_sizes, int n_in,
                              void* d_out, int out_size, void* d_ws, size_t ws_size,
                              hipStream_t stream) {
    const float* in  = (const float*)d_in[0];
    const float* tg  = (const float*)d_in[1];
    const float* mk  = (const float*)d_in[2];
    const float* win = (const float*)d_in[3];
    float* out = (float*)d_out;

    double*   dsum = (double*)d_ws;
    unsigned* dmax = (unsigned*)((char*)d_ws + 8);

    // dsum = 0.0, dmax = 0 (order-encoding floor) in one stream-ordered memset
    hipMemsetAsync(d_ws, 0, 12, stream);
    maxred_kernel<<<4096, 256, 0, stream>>>(in, tg, mk, dmax);
    ssim_kernel<<<dim3(16, 16, 32), 256, 0, stream>>>(in, tg, mk, win, dmax, dsum);
    fin_kernel<<<1, 1, 0, stream>>>(dsum, out);
}

// Round 6
// 158.527 us; speedup vs baseline: 1.3852x; 1.1795x over previous
//
#include <hip/hip_runtime.h>
#include <math.h>

#define H 512
#define W 512
#define NPIX (32LL*512*512)

// vch: [4 strips][6 ch][8 rows][42 cols] = 8064 floats = 32256 B.
// + ssum -> 32768 alloc; 512-thr blocks -> 4 blocks/CU, 32 waves/CU.
#define VCH(s,ch,u,c) uni[(s)*2016 + (ch)*336 + (u)*42 + (c)]

// order-preserving float->uint encoding so we can use native atomicMax(u32).
// enc(x) > 0 for all reals, so a 0-initialized slot acts as -inf.
__device__ inline unsigned encf(float f) {
    unsigned u = __float_as_uint(f);
    return (u & 0x80000000u) ? ~u : (u | 0x80000000u);
}
__device__ inline float decf(unsigned e) {
    unsigned u = (e & 0x80000000u) ? (e ^ 0x80000000u) : ~e;
    return __uint_as_float(u);
}

__global__ __launch_bounds__(256) void maxred_kernel(
        const float* __restrict__ in, const float* __restrict__ tg,
        const float* __restrict__ mk, unsigned* __restrict__ mx) {
    const float4* in4 = (const float4*)in;
    const float4* tg4 = (const float4*)tg;
    const float4* mk4 = (const float4*)mk;
    long long n4 = NPIX / 4;
    long long idx = (long long)blockIdx.x * blockDim.x + threadIdx.x;
    long long stride = (long long)gridDim.x * blockDim.x;
    float ma = -INFINITY, mb = -INFINITY;   // two independent chains
    for (long long i = idx; i < n4; i += stride) {
        float4 a = in4[i], b = tg4[i], c = mk4[i];
        ma = fmaxf(ma, fmaxf(fmaxf(a.x * c.x, a.y * c.y), fmaxf(a.z * c.z, a.w * c.w)));
        mb = fmaxf(mb, fmaxf(fmaxf(b.x * c.x, b.y * c.y), fmaxf(b.z * c.z, b.w * c.w)));
    }
    float m = fmaxf(ma, mb);
    #pragma unroll
    for (int off = 32; off; off >>= 1) m = fmaxf(m, __shfl_down(m, off, 64));
    __shared__ float smax[4];
    int lane = threadIdx.x & 63, wid = threadIdx.x >> 6;
    if (lane == 0) smax[wid] = m;
    __syncthreads();
    if (threadIdx.x == 0) {
        float r = fmaxf(fmaxf(smax[0], smax[1]), fmaxf(smax[2], smax[3]));
        atomicMax(mx, encf(r));
    }
}

// (512,4): empirically the allocator lands at ~256/w = 64 VGPRs -> the 8-wave
// tier the 24-reg accumulator actually fits, with slack for load pipelining.
__global__ __launch_bounds__(512, 4) void ssim_kernel(
        const float* __restrict__ in, const float* __restrict__ tg,
        const float* __restrict__ mk, const float* __restrict__ win,
        const unsigned* __restrict__ mxp, double* __restrict__ sum) {
    __shared__ __align__(16) float uni[8064];
    __shared__ float ssum[8];

    int t = threadIdx.x;
    int lane = t & 63, wid = t >> 6;
    int strip = wid >> 1;        // 0..3: 8-row strip of the 32x32 tile
    int half  = wid & 1;         // 0: accumulate {m,a,b}; 1: {aa,bb,ab}

    // ---- per-wave: separable 1-D gaussian weights -> SGPRs (no LDS, no barrier)
    float rs = 0.f;
    if (lane < 11) {
        #pragma unroll
        for (int j = 0; j < 11; j++) rs += win[lane * 11 + j];
    }
    float wk[11];
    #pragma unroll
    for (int k = 0; k < 11; k++)
        wk[k] = __uint_as_float(__builtin_amdgcn_readfirstlane(
                    __float_as_uint(__shfl(rs, k, 64))));

    // uniform scalar from the max pass (used only in the epilogue)
    float L = decf(*mxp);
    float C3 = 0.5f * (0.03f * L) * (0.03f * L);

    int img = blockIdx.z;
    int y0w = blockIdx.y * 32 + strip * 8;   // this strip's 8 output rows
    int x0  = blockIdx.x * 32;
    const size_t base = (size_t)img * H * W;
    const float* __restrict__ inb = in + base;
    const float* __restrict__ tgb = tg + base;
    const float* __restrict__ mkb = mk + base;

    // ---- vertical blur: wave-pair per strip, 3 channels per wave.
    // lanes 0..41 each own one staged column; acc[3][8] = 24 VGPRs.
    // Partner wave loads the same rows -> L1 hits, no extra HBM traffic.
    if (lane < 42) {
        int x = x0 - 5 + lane;
        bool inx = (unsigned)x < (unsigned)W;
        int xc = inx ? x : 0;                  // clamped: loads always legal
        float xs = inx ? 1.f : 0.f;
        int ybase = y0w - 5;

        float acc[3][8];
        #pragma unroll
        for (int ch = 0; ch < 3; ch++)
            #pragma unroll
            for (int u = 0; u < 8; u++) acc[ch][u] = 0.f;

        if (ybase >= 0 && ybase <= H - 18) {
            // interior fast path: unconditional loads, strength-reduced address
            size_t g = (size_t)ybase * W + xc;
            #pragma unroll
            for (int j = 0; j < 18; j++) {
                float iv = inb[g], tv = tgb[g], m = mkb[g] * xs;
                g += W;
                float a = iv * m, b = tv * m;
                float v0 = half ? a * a : m;       // wave-uniform select
                float v1 = half ? b * b : a;
                float v2 = half ? a * b : b;
                #pragma unroll
                for (int u = 0; u < 8; u++) {
                    int k = j - u;
                    if (k >= 0 && k < 11) {        // compile-time pruned
                        float w = wk[k];
                        acc[0][u] = fmaf(w, v0, acc[0][u]);
                        acc[1][u] = fmaf(w, v1, acc[1][u]);
                        acc[2][u] = fmaf(w, v2, acc[2][u]);
                    }
                }
            }
        } else {
            // y-edge strips (top/bottom of the image only)
            #pragma unroll
            for (int j = 0; j < 18; j++) {
                int y = ybase + j;
                bool yok = (unsigned)y < (unsigned)H;
                size_t g = (size_t)(yok ? y : 0) * W + xc;
                float sc = yok ? xs : 0.f;
                float iv = inb[g], tv = tgb[g], m = mkb[g] * sc;
                float a = iv * m, b = tv * m;
                float v0 = half ? a * a : m;
                float v1 = half ? b * b : a;
                float v2 = half ? a * b : b;
                #pragma unroll
                for (int u = 0; u < 8; u++) {
                    int k = j - u;
                    if (k >= 0 && k < 11) {
                        float w = wk[k];
                        acc[0][u] = fmaf(w, v0, acc[0][u]);
                        acc[1][u] = fmaf(w, v1, acc[1][u]);
                        acc[2][u] = fmaf(w, v2, acc[2][u]);
                    }
                }
            }
        }
        #pragma unroll
        for (int u = 0; u < 8; u++)
            #pragma unroll
            for (int ch = 0; ch < 3; ch++)
                VCH(strip, half * 3 + ch, u, lane) = acc[ch][u];
    }

    __syncthreads();   // cross-wave: hblur needs both halves of each strip

    // ---- horizontal blur + structure map: thread -> (row = t>>4, 2 cols)
    int r  = t >> 4;              // 0..31 global tile row
    int c0 = (t & 15) << 1;       // 0,2,..,30
    int s2 = r >> 3, u2 = r & 7;
    float hs[6][2];
    #pragma unroll
    for (int ch = 0; ch < 6; ch++) {
        float Wl[12];
        #pragma unroll
        for (int q = 0; q < 6; q++) {
            float2 v = *(const float2*)&VCH(s2, ch, u2, c0 + 2 * q);
            Wl[2 * q] = v.x; Wl[2 * q + 1] = v.y;
        }
        #pragma unroll
        for (int u = 0; u < 2; u++) {
            float h = 0.f;
            #pragma unroll
            for (int k = 0; k < 11; k++) h = fmaf(wk[k], Wl[u + k], h);
            hs[ch][u] = h;
        }
    }

    // structure map with num/den multiplied through by mw^2 (no per-pixel divide):
    //   num = hs5*mw - hs1*hs2 + C3*mw^2
    //   den = sqrt(Xi*Xt) + (C3+1e-8)*mw^2,  Xi = max(hs3*mw - hs1^2,0) + 1e-12*mw^2
    float lsum = 0.f;
    #pragma unroll
    for (int u = 0; u < 2; u++) {
        float h1 = hs[1][u], h2 = hs[2][u];
        float mw = hs[0][u] + 1e-8f;
        float mw2 = mw * mw;
        float e12 = 1e-12f * mw2;
        float Xi = fmaxf(fmaf(hs[3][u], mw, -h1 * h1), 0.f) + e12;
        float Xt = fmaxf(fmaf(hs[4][u], mw, -h2 * h2), 0.f) + e12;
        float num = fmaf(hs[5][u], mw, -h1 * h2) + C3 * mw2;
        float den = __builtin_amdgcn_sqrtf(Xi * Xt) + (C3 + 1e-8f) * mw2;
        lsum += num * __builtin_amdgcn_rcpf(den);
    }

    #pragma unroll
    for (int off = 32; off; off >>= 1) lsum += __shfl_down(lsum, off, 64);
    if (lane == 0) ssum[wid] = lsum;
    __syncthreads();                 // final block reduce
    if (t == 0) {
        float tot = 0.f;
        #pragma unroll
        for (int w8 = 0; w8 < 8; w8++) tot += ssum[w8];
        atomicAdd(sum, (double)tot);
    }
}

__global__ void fin_kernel(const double* __restrict__ sum, float* __restrict__ out) {
    out[0] = 1.0f - (float)(*sum / (double)NPIX);
}

extern "C" void kernel_launch(void* const* d_in, const int* in_sizes, int n_in,
                              void* d_out, int out_size, void* d_ws, size_t ws_size,
                              hipStream_t stream) {
    const float* in  = (const float*)d_in[0];
    const float* tg  = (const float*)d_in[1];
    const float* mk  = (const float*)d_in[2];
    const float* win = (const float*)d_in[3];
    float* out = (float*)d_out;

    double*   dsum = (double*)d_ws;
    unsigned* dmax = (unsigned*)((char*)d_ws + 8);

    // dsum = 0.0, dmax = 0 (order-encoding floor) in one stream-ordered memset
    hipMemsetAsync(d_ws, 0, 12, stream);
    maxred_kernel<<<2048, 256, 0, stream>>>(in, tg, mk, dmax);
    ssim_kernel<<<dim3(16, 16, 32), 512, 0, stream>>>(in, tg, mk, win, dmax, dsum);
    fin_kernel<<<1, 1, 0, stream>>>(dsum, out);
}